// Round 21
// baseline (509.017 us; speedup 1.0000x reference)
//
#include <hip/hip_runtime.h>
#include <math.h>

#define RFL(x) __builtin_amdgcn_readfirstlane(x)
#define RL(x, l) __int_as_float(__builtin_amdgcn_readlane(__float_as_int(x), (l)))

typedef __attribute__((ext_vector_type(8))) short bf16x8;
typedef __attribute__((ext_vector_type(4))) float f32x4;

__device__ inline unsigned short bf16_rne(float f) {
  unsigned u = __float_as_uint(f);
  u += 0x7FFFu + ((u >> 16) & 1u);
  return (unsigned short)(u >> 16);
}

// ---------------- degree histogram (int) ----------------

__global__ __launch_bounds__(256) void k_zero(int* p, int n) {
  int t = blockIdx.x * 256 + threadIdx.x;
  if (t < n) p[t] = 0;
}

__global__ __launch_bounds__(256) void k_count(const int* __restrict__ dst, int* cnt, int E) {
  int stride = gridDim.x * blockDim.x;
  for (int e = blockIdx.x * blockDim.x + threadIdx.x; e < E; e += stride)
    atomicAdd(&cnt[dst[e]], 1);
}

// ---------------- scan: cnt -> row_start ----------------

__global__ __launch_bounds__(256) void k_scan1(const int* __restrict__ cnt, int* __restrict__ row,
                                               int* __restrict__ partial, int N) {
  __shared__ int sm[256];
  int t = threadIdx.x, g = blockIdx.x * 256 + t;
  int v = (g < N) ? cnt[g] : 0;
  sm[t] = v;
  __syncthreads();
#pragma unroll
  for (int off = 1; off < 256; off <<= 1) {
    int x = 0;
    if (t >= off) x = sm[t - off];
    __syncthreads();
    if (t >= off) sm[t] += x;
    __syncthreads();
  }
  if (g < N) row[g] = sm[t] - v;  // exclusive within block
  if (t == 255) partial[blockIdx.x] = sm[255];
}

// scan3: adds cross-block prefix (computed in-kernel from partial[0..bid)),
// writes row/cursor, and dinv.
__global__ __launch_bounds__(256) void k_scan3(int* __restrict__ row, const int* __restrict__ partial,
                                               int* __restrict__ cursor, const int* __restrict__ cnt,
                                               float* __restrict__ dinv, int N) {
  __shared__ int red[256];
  const int t = threadIdx.x;
  int acc = 0;
  for (int i = t; i < blockIdx.x; i += 256) acc += partial[i];
  red[t] = acc;
  __syncthreads();
#pragma unroll
  for (int off = 128; off > 0; off >>= 1) {
    if (t < off) red[t] += red[t + off];
    __syncthreads();
  }
  const int base = red[0];
  int g = blockIdx.x * 256 + t;
  if (g < N) {
    int v = row[g] + base;
    row[g] = v;
    cursor[g] = v;
    dinv[g] = rsqrtf((float)cnt[g] + 1.0f);  // +1 self-loop
  }
}

// ---------------- edge placement: dst-sorted src ----------------

__global__ __launch_bounds__(256) void k_edge_fill(const int* __restrict__ src, const int* __restrict__ dst,
                                                   int* __restrict__ cursor, int* __restrict__ esrc, int E) {
  int stride = gridDim.x * blockDim.x;
  for (int e = blockIdx.x * blockDim.x + threadIdx.x; e < E; e += stride) {
    int s = src[e], d = dst[e];
    int pos = atomicAdd(&cursor[d], 1);
    esrc[pos] = s;
  }
}

// ---------------- W_c = W_out @ W1, b_c = b_out @ W1 ----------------

__global__ __launch_bounds__(256) void k_wc(const float* __restrict__ Wout, const float* __restrict__ bout,
                                            const float* __restrict__ W1, float* __restrict__ Wc,
                                            float* __restrict__ bc) {
  int t = blockIdx.x * 256 + threadIdx.x;
  if (t >= 65 * 128) return;
  int h = t >> 7, o = t & 127;
  const float* row = (h < 64) ? (Wout + h * 128) : bout;
  float a = 0.f;
  for (int d = 0; d < 128; ++d) a += row[d] * W1[d * 128 + o];
  if (h < 64) Wc[h * 128 + o] = a;
  else bc[o] = a;
}

// ---------------- attention pooling via MFMA, persistent+pipelined ----------------
// R21: R19's exact schedule, but next-tile loads REUSE xv in place (xv is dead
// after the convert; load issued at the identical program point). Register
// demand ~116 < 128 -> __launch_bounds__(256,4), grid 1024: 4 blocks/CU,
// 16 waves/CU (+33% latency hiding) at unchanged memory/barrier schedule.

__global__ __launch_bounds__(256, 4) void k_pool(const float* __restrict__ X, const int* __restrict__ mask,
                                                 const float* __restrict__ WE, const float* __restrict__ bE,
                                                 const float* __restrict__ WA, const float* __restrict__ bA,
                                                 const float* __restrict__ dinv, float* __restrict__ pzp, int N) {
  __shared__ __align__(16) unsigned short Xh[80][136];
  __shared__ float scorep[80][4];
  __shared__ float sco[80];
  __shared__ float wgtA[80];
  float* zt = (float*)&Xh[0][0];  // alias: 80*68 f32 = 21760B = sizeof(Xh)

  const int t = threadIdx.x;
  const int lane = t & 63;
  const int wv = t >> 6;     // wave 0..3 = col tile
  const int cb = wv * 16;
  const int l16 = lane & 15;
  const int lg = lane >> 4;  // 0..3

  const long long totRows = (long long)N * 20;
  const int numTiles = (N + 3) / 4;

  const int r0 = t >> 5;            // rows r0, r0+8, ..., r0+72
  const int kq4 = (t & 31) * 4;     // float col base

  bf16x8 bh[4], bl[4];
#pragma unroll
  for (int kk = 0; kk < 4; ++kk) {
    union { bf16x8 v; unsigned short s[8]; } uh, ul;
#pragma unroll
    for (int i = 0; i < 8; ++i) {
      int k = kk * 32 + lg * 8 + i;
      float w = WE[k * 64 + cb + l16];
      unsigned short h = bf16_rne(w);
      uh.s[i] = h;
      ul.s[i] = bf16_rne(w - __uint_as_float((unsigned)h << 16));
    }
    bh[kk] = uh.v;
    bl[kk] = ul.v;
  }
  const float bEv = bE[cb + l16];
  const float WAv = WA[cb + l16];
  const float bAv = bA[0];
  const float NEG = -3.0e38f;

  int tile = blockIdx.x;
  if (tile >= numTiles) return;

  // prologue: load tile0 into xv
  float4 xv[10];
#pragma unroll
  for (int q = 0; q < 10; ++q) {
    long long rr = (long long)tile * 80 + r0 + q * 8;
    if (rr >= totRows) rr = totRows - 1;
    xv[q] = *(const float4*)(X + rr * 128 + kq4);
  }
  int mkcur = 1;
  {
    long long mi = (long long)tile * 80 + t;
    if (t < 80) mkcur = (mi < totRows) ? mask[mi] : 0;
  }

  while (true) {
    // ---- convert current tile (in xv) -> LDS (plain bf16); xv dead after ----
#pragma unroll
    for (int q = 0; q < 10; ++q) {
      const int r = r0 + q * 8;
      const float4 v = xv[q];
      *(ushort4*)&Xh[r][kq4] = make_ushort4(bf16_rne(v.x), bf16_rne(v.y), bf16_rne(v.z), bf16_rne(v.w));
    }
    __syncthreads();  // staging done

    // ---- issue next tile's loads directly into xv (latency hidden under MFMA+epilogue) ----
    const int nextTile = tile + gridDim.x;
    const bool hasNext = nextTile < numTiles;
    int mknext = 1;
    {
      const long long nb = (long long)(hasNext ? nextTile : tile) * 80;
#pragma unroll
      for (int q = 0; q < 10; ++q) {
        long long rr = nb + r0 + q * 8;
        if (rr >= totRows) rr = totRows - 1;
        xv[q] = *(const float4*)(X + rr * 128 + kq4);
      }
      long long mi = nb + t;
      if (t < 80) mknext = (mi < totRows) ? mask[mi] : 0;
    }

    // ---- MFMA: Z[80][16 cols of this wave] ----
    f32x4 acc[5];
#pragma unroll
    for (int rt = 0; rt < 5; ++rt) acc[rt] = (f32x4){0.f, 0.f, 0.f, 0.f};
#pragma unroll
    for (int rt = 0; rt < 5; ++rt) {
      const int rl = rt * 16 + l16;
#pragma unroll
      for (int kk = 0; kk < 4; ++kk) {
        const int ko = kk * 32 + lg * 8;
        bf16x8 ah = *(const bf16x8*)&Xh[rl][ko];
        acc[rt] = __builtin_amdgcn_mfma_f32_16x16x32_bf16(ah, bh[kk], acc[rt], 0, 0, 0);
        acc[rt] = __builtin_amdgcn_mfma_f32_16x16x32_bf16(ah, bl[kk], acc[rt], 0, 0, 0);
      }
    }

#pragma unroll
    for (int rt = 0; rt < 5; ++rt) {
#pragma unroll
      for (int j = 0; j < 4; ++j) {
        float z = fmaxf(acc[rt][j] + bEv, 0.f);
        acc[rt][j] = z;
        float v = z * WAv;
        v += __shfl_xor(v, 1, 64);
        v += __shfl_xor(v, 2, 64);
        v += __shfl_xor(v, 4, 64);
        v += __shfl_xor(v, 8, 64);
        if (l16 == 0) scorep[rt * 16 + lg * 4 + j][wv] = v;
      }
    }
    __syncthreads();  // barrier 1: MFMA's Xh reads done + scorep visible

#pragma unroll
    for (int rt = 0; rt < 5; ++rt) {
#pragma unroll
      for (int j = 0; j < 4; ++j) {
        int row = rt * 16 + lg * 4 + j;
        zt[row * 68 + cb + l16] = acc[rt][j];
      }
    }
    if (t < 80) {
      float4 sp = *(const float4*)scorep[t];
      float sc = sp.x + sp.y + sp.z + sp.w + bAv;
      if (mkcur == 0) sc = NEG;
      sco[t] = sc;
    }
    __syncthreads();  // barrier 2

    if (t < 80) {
      const int base = (t / 20) * 20;
      float mx = NEG;
#pragma unroll
      for (int i = 0; i < 20; ++i) mx = fmaxf(mx, sco[base + i]);
      float den = 0.f;
#pragma unroll
      for (int i = 0; i < 20; ++i) den += __expf(sco[base + i] - mx);
      wgtA[t] = __expf(sco[t] - mx) / den;
    }
    __syncthreads();  // barrier 3

    {
      int n = t >> 6, col = t & 63;
      long long node = (long long)tile * 4 + n;
      if (node < N) {
        float s = 0.f;
#pragma unroll
        for (int i = 0; i < 20; ++i) s += zt[(n * 20 + i) * 68 + col] * wgtA[n * 20 + i];
        pzp[node * 64 + col] = s * dinv[node];
      }
    }

    if (!hasNext) break;
    __syncthreads();  // barrier 4: zt reads done before next convert writes Xh
    mkcur = mknext;
    tile = nextTile;
  }
}

// ---------------- gather layer 1 (64-dim) + g vector ----------------

__global__ __launch_bounds__(256) void k_gather1(const int* __restrict__ row, const int* __restrict__ cnt,
                                                 const int* __restrict__ esrc, const float* __restrict__ pzp,
                                                 const float* __restrict__ dinv, float* __restrict__ y,
                                                 float* __restrict__ gout, int N) {
  const int lane = threadIdx.x & 63;
  const int node = RFL(blockIdx.x * 4 + (threadIdx.x >> 6));
  if (node >= N) return;
  const int q = lane >> 4, f4 = lane & 15;  // group 0..3, float4 slot 0..15
  const int rs = RFL(row[node]);
  const int ne = RFL(cnt[node]);
  const float di = dinv[node];
  const float4* __restrict__ hv = (const float4*)pzp;
  float a0 = 0.f, a1 = 0.f, a2 = 0.f, a3 = 0.f, ds = 0.f;
  int j = 0;
  for (; j + 16 <= ne; j += 16) {
    const int b = rs + j + q * 4;
    int s[4];
#pragma unroll
    for (int u = 0; u < 4; ++u) s[u] = esrc[b + u];
    float4 v[4];
#pragma unroll
    for (int u = 0; u < 4; ++u) v[u] = hv[(size_t)s[u] * 16 + f4];
#pragma unroll
    for (int u = 0; u < 4; ++u) {
      a0 += v[u].x; a1 += v[u].y; a2 += v[u].z; a3 += v[u].w;
      ds += dinv[s[u]];
    }
  }
  if (j < ne) {
    const int b = j + q * 4;
    int s[4];
    float m[4];
#pragma unroll
    for (int u = 0; u < 4; ++u) {
      int idx = b + u;
      int c = (idx < ne) ? idx : (ne - 1);
      s[u] = esrc[rs + c];
      m[u] = (idx < ne) ? 1.f : 0.f;
    }
    float4 v[4];
#pragma unroll
    for (int u = 0; u < 4; ++u) v[u] = hv[(size_t)s[u] * 16 + f4];
#pragma unroll
    for (int u = 0; u < 4; ++u) {
      a0 += v[u].x * m[u]; a1 += v[u].y * m[u]; a2 += v[u].z * m[u]; a3 += v[u].w * m[u];
      ds += dinv[s[u]] * m[u];
    }
  }
  a0 += __shfl_xor(a0, 16, 64); a0 += __shfl_xor(a0, 32, 64);
  a1 += __shfl_xor(a1, 16, 64); a1 += __shfl_xor(a1, 32, 64);
  a2 += __shfl_xor(a2, 16, 64); a2 += __shfl_xor(a2, 32, 64);
  a3 += __shfl_xor(a3, 16, 64); a3 += __shfl_xor(a3, 32, 64);
  ds += __shfl_xor(ds, 16, 64); ds += __shfl_xor(ds, 32, 64);
  if (lane < 16) {
    float4 sv = hv[(size_t)node * 16 + f4];
    float4 o;
    o.x = (a0 + sv.x * di) * di;
    o.y = (a1 + sv.y * di) * di;
    o.z = (a2 + sv.z * di) * di;
    o.w = (a3 + sv.w * di) * di;
    ((float4*)y)[(size_t)node * 16 + f4] = o;
    if (f4 == 0) gout[node] = di * (ds + di * di);
  }
}

// ---------------- x1 = y @ Wc + g * bc ----------------

__global__ __launch_bounds__(256, 2) void k_gemm1(const float* __restrict__ y, const float* __restrict__ gin,
                                                  const float* __restrict__ Wc, const float* __restrict__ bc,
                                                  float* __restrict__ x1, int N) {
  const int lane = threadIdx.x & 63;
  float w0[64], w1[64];
#pragma unroll
  for (int d = 0; d < 64; ++d) {
    w0[d] = Wc[d * 128 + lane];
    w1[d] = Wc[d * 128 + 64 + lane];
  }
  const float b0 = bc[lane], b1v = bc[64 + lane];
  const int nw = (gridDim.x * blockDim.x) >> 6;
  const int w_id = (blockIdx.x * blockDim.x + threadIdx.x) >> 6;
  for (int r = w_id; r < N; r += nw) {
    const float xv = y[(size_t)r * 64 + lane];
    const float gr = gin[r];
    const int xi = __float_as_int(xv);
    float p0 = 0.f, p1 = 0.f, p2 = 0.f, p3 = 0.f;
#pragma unroll
    for (int d0 = 0; d0 < 64; d0 += 2) {
      float a0 = RL((float&)xi, d0);
      float a1 = RL((float&)xi, d0 + 1);
      p0 += a0 * w0[d0];
      p1 += a0 * w1[d0];
      p2 += a1 * w0[d0 + 1];
      p3 += a1 * w1[d0 + 1];
    }
    size_t o = (size_t)r * 128 + lane;
    x1[o] = p0 + p2 + gr * b0;
    x1[o + 64] = p1 + p3 + gr * b1v;
  }
}

// ---------------- h2p = (relu(x1 + b1) @ W2) * dinv[r] ----------------

__global__ __launch_bounds__(256, 2) void k_gemm2(const float* __restrict__ x1, const float* __restrict__ b1,
                                                  const float* __restrict__ W2, const float* __restrict__ dinv,
                                                  float* __restrict__ h2p, int N) {
  const int lane = threadIdx.x & 63;
  const int col = lane & 31;
  float w[128];
#pragma unroll
  for (int d = 0; d < 128; ++d) w[d] = W2[d * 32 + col];
  const float bb0 = b1[lane], bb1 = b1[64 + lane];
  const int nw = (gridDim.x * blockDim.x) >> 6;
  const int w_id = (blockIdx.x * blockDim.x + threadIdx.x) >> 6;
  for (int r = w_id; r < N; r += nw) {
    float rx0 = fmaxf(x1[(size_t)r * 128 + lane] + bb0, 0.f);
    float rx1 = fmaxf(x1[(size_t)r * 128 + 64 + lane] + bb1, 0.f);
    const int xi0 = __float_as_int(rx0), xi1 = __float_as_int(rx1);
    float p0 = 0.f, p1 = 0.f, p2 = 0.f, p3 = 0.f;
#pragma unroll
    for (int d0 = 0; d0 < 64; d0 += 2) {
      float a0 = RL((float&)xi0, d0);
      float a1 = RL((float&)xi0, d0 + 1);
      float c0 = RL((float&)xi1, d0);
      float c1 = RL((float&)xi1, d0 + 1);
      p0 += a0 * w[d0];
      p1 += a1 * w[d0 + 1];
      p2 += c0 * w[64 + d0];
      p3 += c1 * w[64 + d0 + 1];
    }
    if (lane < 32) {
      float di = dinv[r];
      h2p[(size_t)r * 32 + col] = ((p0 + p1) + (p2 + p3)) * di;
    }
  }
}

// ---------------- fused layer-2 gather + query MLP ----------------

__global__ __launch_bounds__(256) void k_gmlp(const int* __restrict__ qidx, const int* __restrict__ row,
                                              const int* __restrict__ cnt, const int* __restrict__ esrc,
                                              const float* __restrict__ h2p, const float* __restrict__ dinv,
                                              const float* __restrict__ b2, const float* __restrict__ Wm1,
                                              const float* __restrict__ bm1, const float* __restrict__ Wm2,
                                              const float* __restrict__ bm2, float* __restrict__ out, int B) {
  __shared__ float qs[4][32];
  const int lane = threadIdx.x & 63;
  const int wv = threadIdx.x >> 6;
  const int w = blockIdx.x * 4 + wv;            // query id
  const int wc = (w < B) ? w : (B - 1);         // clamp (keep block barrier-uniform)
  const int node = RFL(qidx[wc]);

  const int q = lane >> 3, f4 = lane & 7;       // group 0..7, float4 slot 0..7
  const int rs = RFL(row[node]);
  const int ne = RFL(cnt[node]);
  const float di = dinv[node];
  const float4* __restrict__ hv = (const float4*)h2p;
  float a0 = 0.f, a1 = 0.f, a2 = 0.f, a3 = 0.f;
  int j = 0;
  for (; j + 32 <= ne; j += 32) {
    const int b = rs + j + q * 4;
    int s[4];
#pragma unroll
    for (int u = 0; u < 4; ++u) s[u] = esrc[b + u];
    float4 v[4];
#pragma unroll
    for (int u = 0; u < 4; ++u) v[u] = hv[(size_t)s[u] * 8 + f4];
#pragma unroll
    for (int u = 0; u < 4; ++u) {
      a0 += v[u].x; a1 += v[u].y; a2 += v[u].z; a3 += v[u].w;
    }
  }
  if (j < ne) {
    const int b = j + q * 4;
    int s[4];
    float m[4];
#pragma unroll
    for (int u = 0; u < 4; ++u) {
      int idx = b + u;
      int c = (idx < ne) ? idx : (ne - 1);
      s[u] = esrc[rs + c];
      m[u] = (idx < ne) ? 1.f : 0.f;
    }
    float4 v[4];
#pragma unroll
    for (int u = 0; u < 4; ++u) v[u] = hv[(size_t)s[u] * 8 + f4];
#pragma unroll
    for (int u = 0; u < 4; ++u) {
      a0 += v[u].x * m[u]; a1 += v[u].y * m[u]; a2 += v[u].z * m[u]; a3 += v[u].w * m[u];
    }
  }
#pragma unroll
  for (int off = 8; off <= 32; off <<= 1) {
    a0 += __shfl_xor(a0, off, 64);
    a1 += __shfl_xor(a1, off, 64);
    a2 += __shfl_xor(a2, off, 64);
    a3 += __shfl_xor(a3, off, 64);
  }
  if (q == 0) {  // lanes 0..7 hold the final x2 float4s
    float4 sv = hv[(size_t)node * 8 + f4];
    qs[wv][f4 * 4 + 0] = fmaxf((a0 + sv.x * di) * di + b2[f4 * 4 + 0], 0.f);
    qs[wv][f4 * 4 + 1] = fmaxf((a1 + sv.y * di) * di + b2[f4 * 4 + 1], 0.f);
    qs[wv][f4 * 4 + 2] = fmaxf((a2 + sv.z * di) * di + b2[f4 * 4 + 2], 0.f);
    qs[wv][f4 * 4 + 3] = fmaxf((a3 + sv.w * di) * di + b2[f4 * 4 + 3], 0.f);
  }
  __syncthreads();

  float h = bm1[lane];
#pragma unroll
  for (int k = 0; k < 32; ++k) h += qs[wv][k] * Wm1[k * 64 + lane];
  float r = fmaxf(h, 0.f) * Wm2[lane];
#pragma unroll
  for (int off = 1; off < 64; off <<= 1) r += __shfl_xor(r, off, 64);
  if (lane == 0 && w < B) out[w] = r + bm2[0];
}

// ---------------- launcher ----------------

extern "C" void kernel_launch(void* const* d_in, const int* in_sizes, int n_in,
                              void* d_out, int out_size, void* d_ws, size_t ws_size,
                              hipStream_t stream) {
  const float* X    = (const float*)d_in[0];
  const int*   mask = (const int*)d_in[1];
  const int*   ei   = (const int*)d_in[2];
  const int*   qidx = (const int*)d_in[3];
  const float* WE   = (const float*)d_in[4];
  const float* bE   = (const float*)d_in[5];
  const float* WA   = (const float*)d_in[6];
  const float* bA   = (const float*)d_in[7];
  const float* Wout = (const float*)d_in[8];
  const float* bout = (const float*)d_in[9];
  const float* W1   = (const float*)d_in[10];
  const float* b1   = (const float*)d_in[11];
  const float* W2   = (const float*)d_in[12];
  const float* b2   = (const float*)d_in[13];
  const float* Wm1  = (const float*)d_in[14];
  const float* bm1  = (const float*)d_in[15];
  const float* Wm2  = (const float*)d_in[16];
  const float* bm2  = (const float*)d_in[17];

  const int N = in_sizes[1] / 20;
  const int E = in_sizes[2] / 2;
  const int B = in_sizes[3];
  const int* src  = ei;
  const int* dstp = ei + E;

  const size_t Na = ((size_t)N + 63) & ~(size_t)63;
  const size_t Ea = ((size_t)E + 63) & ~(size_t)63;
  const int P = (N + 255) / 256;
  const size_t Pa = ((size_t)P + 63) & ~(size_t)63;

  float* ws      = (float*)d_ws;
  float* dinv    = ws;                       // N
  int*   cnt     = (int*)(dinv + Na);        // N
  int*   rowp    = cnt + Na;                 // N
  int*   cursor  = rowp + Na;                // N
  int*   partial = cursor + Na;              // P
  int*   esrc    = partial + Pa;             // E
  float* Wc      = (float*)(esrc + Ea);      // 8192
  float* bc      = Wc + 8192;                // 128
  float* gbuf    = bc + 128;                 // N
  float* pzp     = gbuf + Na;                // N*64
  float* y       = pzp + (size_t)N * 64;     // N*64
  float* x1      = y + (size_t)N * 64;       // N*128
  float* h2p     = pzp;                      // reuse pzp (dead after gather1): N*32

  const int nb = (N + 255) / 256;
  const int nw4 = (N + 3) / 4;
  const int poolBlocks = ((N + 3) / 4 < 1024) ? (N + 3) / 4 : 1024;

  k_zero<<<nb, 256, 0, stream>>>(cnt, N);
  k_count<<<1024, 256, 0, stream>>>(dstp, cnt, E);
  k_scan1<<<P, 256, 0, stream>>>(cnt, rowp, partial, N);
  k_scan3<<<P, 256, 0, stream>>>(rowp, partial, cursor, cnt, dinv, N);
  k_edge_fill<<<2048, 256, 0, stream>>>(src, dstp, cursor, esrc, E);
  k_wc<<<33, 256, 0, stream>>>(Wout, bout, W1, Wc, bc);
  k_pool<<<poolBlocks, 256, 0, stream>>>(X, mask, WE, bE, WA, bA, dinv, pzp, N);
  k_gather1<<<nw4, 256, 0, stream>>>(rowp, cnt, esrc, pzp, dinv, y, gbuf, N);
  k_gemm1<<<1024, 256, 0, stream>>>(y, gbuf, Wc, bc, x1, N);
  k_gemm2<<<1024, 256, 0, stream>>>(x1, b1, W2, dinv, h2p, N);
  k_gmlp<<<(B + 3) / 4, 256, 0, stream>>>(qidx, rowp, cnt, esrc, h2p, dinv, b2, Wm1, bm1, Wm2, bm2,
                                          (float*)d_out, B);
}

// Round 22
// 457.709 us; speedup vs baseline: 1.1121x; 1.1121x over previous
//
#include <hip/hip_runtime.h>
#include <math.h>

#define RFL(x) __builtin_amdgcn_readfirstlane(x)
#define RL(x, l) __int_as_float(__builtin_amdgcn_readlane(__float_as_int(x), (l)))

typedef __attribute__((ext_vector_type(8))) short bf16x8;
typedef __attribute__((ext_vector_type(4))) float f32x4;

__device__ inline unsigned short bf16_rne(float f) {
  unsigned u = __float_as_uint(f);
  u += 0x7FFFu + ((u >> 16) & 1u);
  return (unsigned short)(u >> 16);
}

// ---------------- degree histogram (int) ----------------

__global__ __launch_bounds__(256) void k_zero(int* p, int n) {
  int t = blockIdx.x * 256 + threadIdx.x;
  if (t < n) p[t] = 0;
}

__global__ __launch_bounds__(256) void k_count(const int* __restrict__ dst, int* cnt, int E) {
  int stride = gridDim.x * blockDim.x;
  for (int e = blockIdx.x * blockDim.x + threadIdx.x; e < E; e += stride)
    atomicAdd(&cnt[dst[e]], 1);
}

// ---------------- scan: cnt -> row_start ----------------

__global__ __launch_bounds__(256) void k_scan1(const int* __restrict__ cnt, int* __restrict__ row,
                                               int* __restrict__ partial, int N) {
  __shared__ int sm[256];
  int t = threadIdx.x, g = blockIdx.x * 256 + t;
  int v = (g < N) ? cnt[g] : 0;
  sm[t] = v;
  __syncthreads();
#pragma unroll
  for (int off = 1; off < 256; off <<= 1) {
    int x = 0;
    if (t >= off) x = sm[t - off];
    __syncthreads();
    if (t >= off) sm[t] += x;
    __syncthreads();
  }
  if (g < N) row[g] = sm[t] - v;  // exclusive within block
  if (t == 255) partial[blockIdx.x] = sm[255];
}

// scan3: adds cross-block prefix (computed in-kernel from partial[0..bid)),
// writes row/cursor, and dinv.
__global__ __launch_bounds__(256) void k_scan3(int* __restrict__ row, const int* __restrict__ partial,
                                               int* __restrict__ cursor, const int* __restrict__ cnt,
                                               float* __restrict__ dinv, int N) {
  __shared__ int red[256];
  const int t = threadIdx.x;
  int acc = 0;
  for (int i = t; i < blockIdx.x; i += 256) acc += partial[i];
  red[t] = acc;
  __syncthreads();
#pragma unroll
  for (int off = 128; off > 0; off >>= 1) {
    if (t < off) red[t] += red[t + off];
    __syncthreads();
  }
  const int base = red[0];
  int g = blockIdx.x * 256 + t;
  if (g < N) {
    int v = row[g] + base;
    row[g] = v;
    cursor[g] = v;
    dinv[g] = rsqrtf((float)cnt[g] + 1.0f);  // +1 self-loop
  }
}

// ---------------- edge placement: dst-sorted src ----------------

__global__ __launch_bounds__(256) void k_edge_fill(const int* __restrict__ src, const int* __restrict__ dst,
                                                   int* __restrict__ cursor, int* __restrict__ esrc, int E) {
  int stride = gridDim.x * blockDim.x;
  for (int e = blockIdx.x * blockDim.x + threadIdx.x; e < E; e += stride) {
    int s = src[e], d = dst[e];
    int pos = atomicAdd(&cursor[d], 1);
    esrc[pos] = s;
  }
}

// ---------------- W_c = W_out @ W1, b_c = b_out @ W1 ----------------

__global__ __launch_bounds__(256) void k_wc(const float* __restrict__ Wout, const float* __restrict__ bout,
                                            const float* __restrict__ W1, float* __restrict__ Wc,
                                            float* __restrict__ bc) {
  int t = blockIdx.x * 256 + threadIdx.x;
  if (t >= 65 * 128) return;
  int h = t >> 7, o = t & 127;
  const float* row = (h < 64) ? (Wout + h * 128) : bout;
  float a = 0.f;
  for (int d = 0; d < 128; ++d) a += row[d] * W1[d * 128 + o];
  if (h < 64) Wc[h * 128 + o] = a;
  else bc[o] = a;
}

// ---------------- attention pooling via MFMA, persistent+pipelined ----------------
// R22 = R19 exact revert (best measured: 462us). bf16-only X (numerics verified),
// __launch_bounds__(256,3), grid 768: VGPR cap ~168 keeps the xv/xn 2-deep
// register prefetch pipeline live. Six scheduling restructures (R11/R12/R16/
// R18/R20/R21) all measured neutral-or-worse; this is the local optimum.

__global__ __launch_bounds__(256, 3) void k_pool(const float* __restrict__ X, const int* __restrict__ mask,
                                                 const float* __restrict__ WE, const float* __restrict__ bE,
                                                 const float* __restrict__ WA, const float* __restrict__ bA,
                                                 const float* __restrict__ dinv, float* __restrict__ pzp, int N) {
  __shared__ __align__(16) unsigned short Xh[80][136];
  __shared__ float scorep[80][4];
  __shared__ float sco[80];
  __shared__ float wgtA[80];
  float* zt = (float*)&Xh[0][0];  // alias: 80*68 f32 = 21760B = sizeof(Xh)

  const int t = threadIdx.x;
  const int lane = t & 63;
  const int wv = t >> 6;     // wave 0..3 = col tile
  const int cb = wv * 16;
  const int l16 = lane & 15;
  const int lg = lane >> 4;  // 0..3

  const long long totRows = (long long)N * 20;
  const int numTiles = (N + 3) / 4;

  const int r0 = t >> 5;            // rows r0, r0+8, ..., r0+72
  const int kq4 = (t & 31) * 4;     // float col base

  bf16x8 bh[4], bl[4];
#pragma unroll
  for (int kk = 0; kk < 4; ++kk) {
    union { bf16x8 v; unsigned short s[8]; } uh, ul;
#pragma unroll
    for (int i = 0; i < 8; ++i) {
      int k = kk * 32 + lg * 8 + i;
      float w = WE[k * 64 + cb + l16];
      unsigned short h = bf16_rne(w);
      uh.s[i] = h;
      ul.s[i] = bf16_rne(w - __uint_as_float((unsigned)h << 16));
    }
    bh[kk] = uh.v;
    bl[kk] = ul.v;
  }
  const float bEv = bE[cb + l16];
  const float WAv = WA[cb + l16];
  const float bAv = bA[0];
  const float NEG = -3.0e38f;

  int tile = blockIdx.x;
  if (tile >= numTiles) return;

  float4 xv[10];
#pragma unroll
  for (int q = 0; q < 10; ++q) {
    long long rr = (long long)tile * 80 + r0 + q * 8;
    if (rr >= totRows) rr = totRows - 1;
    xv[q] = *(const float4*)(X + rr * 128 + kq4);
  }
  int mkcur = 1;
  {
    long long mi = (long long)tile * 80 + t;
    if (t < 80) mkcur = (mi < totRows) ? mask[mi] : 0;
  }

  while (true) {
    // ---- convert current tile -> LDS (plain bf16) ----
#pragma unroll
    for (int q = 0; q < 10; ++q) {
      const int r = r0 + q * 8;
      const float4 v = xv[q];
      *(ushort4*)&Xh[r][kq4] = make_ushort4(bf16_rne(v.x), bf16_rne(v.y), bf16_rne(v.z), bf16_rne(v.w));
    }
    __syncthreads();  // staging done

    const int nextTile = tile + gridDim.x;
    const bool hasNext = nextTile < numTiles;
    float4 xn[10];
    int mknext = 1;
    {
      const long long nb = (long long)(hasNext ? nextTile : tile) * 80;
#pragma unroll
      for (int q = 0; q < 10; ++q) {
        long long rr = nb + r0 + q * 8;
        if (rr >= totRows) rr = totRows - 1;
        xn[q] = *(const float4*)(X + rr * 128 + kq4);
      }
      long long mi = nb + t;
      if (t < 80) mknext = (mi < totRows) ? mask[mi] : 0;
    }

    // ---- MFMA: Z[80][16 cols of this wave] ----
    f32x4 acc[5];
#pragma unroll
    for (int rt = 0; rt < 5; ++rt) acc[rt] = (f32x4){0.f, 0.f, 0.f, 0.f};
#pragma unroll
    for (int rt = 0; rt < 5; ++rt) {
      const int rl = rt * 16 + l16;
#pragma unroll
      for (int kk = 0; kk < 4; ++kk) {
        const int ko = kk * 32 + lg * 8;
        bf16x8 ah = *(const bf16x8*)&Xh[rl][ko];
        acc[rt] = __builtin_amdgcn_mfma_f32_16x16x32_bf16(ah, bh[kk], acc[rt], 0, 0, 0);
        acc[rt] = __builtin_amdgcn_mfma_f32_16x16x32_bf16(ah, bl[kk], acc[rt], 0, 0, 0);
      }
    }

#pragma unroll
    for (int rt = 0; rt < 5; ++rt) {
#pragma unroll
      for (int j = 0; j < 4; ++j) {
        float z = fmaxf(acc[rt][j] + bEv, 0.f);
        acc[rt][j] = z;
        float v = z * WAv;
        v += __shfl_xor(v, 1, 64);
        v += __shfl_xor(v, 2, 64);
        v += __shfl_xor(v, 4, 64);
        v += __shfl_xor(v, 8, 64);
        if (l16 == 0) scorep[rt * 16 + lg * 4 + j][wv] = v;
      }
    }
    __syncthreads();  // barrier 1

#pragma unroll
    for (int rt = 0; rt < 5; ++rt) {
#pragma unroll
      for (int j = 0; j < 4; ++j) {
        int row = rt * 16 + lg * 4 + j;
        zt[row * 68 + cb + l16] = acc[rt][j];
      }
    }
    if (t < 80) {
      float4 sp = *(const float4*)scorep[t];
      float sc = sp.x + sp.y + sp.z + sp.w + bAv;
      if (mkcur == 0) sc = NEG;
      sco[t] = sc;
    }
    __syncthreads();  // barrier 2

    if (t < 80) {
      const int base = (t / 20) * 20;
      float mx = NEG;
#pragma unroll
      for (int i = 0; i < 20; ++i) mx = fmaxf(mx, sco[base + i]);
      float den = 0.f;
#pragma unroll
      for (int i = 0; i < 20; ++i) den += __expf(sco[base + i] - mx);
      wgtA[t] = __expf(sco[t] - mx) / den;
    }
    __syncthreads();  // barrier 3

    {
      int n = t >> 6, col = t & 63;
      long long node = (long long)tile * 4 + n;
      if (node < N) {
        float s = 0.f;
#pragma unroll
        for (int i = 0; i < 20; ++i) s += zt[(n * 20 + i) * 68 + col] * wgtA[n * 20 + i];
        pzp[node * 64 + col] = s * dinv[node];
      }
    }

    if (!hasNext) break;
    __syncthreads();  // barrier 4
#pragma unroll
    for (int q = 0; q < 10; ++q) xv[q] = xn[q];
    mkcur = mknext;
    tile = nextTile;
  }
}

// ---------------- gather layer 1 (64-dim) + g vector ----------------

__global__ __launch_bounds__(256) void k_gather1(const int* __restrict__ row, const int* __restrict__ cnt,
                                                 const int* __restrict__ esrc, const float* __restrict__ pzp,
                                                 const float* __restrict__ dinv, float* __restrict__ y,
                                                 float* __restrict__ gout, int N) {
  const int lane = threadIdx.x & 63;
  const int node = RFL(blockIdx.x * 4 + (threadIdx.x >> 6));
  if (node >= N) return;
  const int q = lane >> 4, f4 = lane & 15;  // group 0..3, float4 slot 0..15
  const int rs = RFL(row[node]);
  const int ne = RFL(cnt[node]);
  const float di = dinv[node];
  const float4* __restrict__ hv = (const float4*)pzp;
  float a0 = 0.f, a1 = 0.f, a2 = 0.f, a3 = 0.f, ds = 0.f;
  int j = 0;
  for (; j + 16 <= ne; j += 16) {
    const int b = rs + j + q * 4;
    int s[4];
#pragma unroll
    for (int u = 0; u < 4; ++u) s[u] = esrc[b + u];
    float4 v[4];
#pragma unroll
    for (int u = 0; u < 4; ++u) v[u] = hv[(size_t)s[u] * 16 + f4];
#pragma unroll
    for (int u = 0; u < 4; ++u) {
      a0 += v[u].x; a1 += v[u].y; a2 += v[u].z; a3 += v[u].w;
      ds += dinv[s[u]];
    }
  }
  if (j < ne) {
    const int b = j + q * 4;
    int s[4];
    float m[4];
#pragma unroll
    for (int u = 0; u < 4; ++u) {
      int idx = b + u;
      int c = (idx < ne) ? idx : (ne - 1);
      s[u] = esrc[rs + c];
      m[u] = (idx < ne) ? 1.f : 0.f;
    }
    float4 v[4];
#pragma unroll
    for (int u = 0; u < 4; ++u) v[u] = hv[(size_t)s[u] * 16 + f4];
#pragma unroll
    for (int u = 0; u < 4; ++u) {
      a0 += v[u].x * m[u]; a1 += v[u].y * m[u]; a2 += v[u].z * m[u]; a3 += v[u].w * m[u];
      ds += dinv[s[u]] * m[u];
    }
  }
  a0 += __shfl_xor(a0, 16, 64); a0 += __shfl_xor(a0, 32, 64);
  a1 += __shfl_xor(a1, 16, 64); a1 += __shfl_xor(a1, 32, 64);
  a2 += __shfl_xor(a2, 16, 64); a2 += __shfl_xor(a2, 32, 64);
  a3 += __shfl_xor(a3, 16, 64); a3 += __shfl_xor(a3, 32, 64);
  ds += __shfl_xor(ds, 16, 64); ds += __shfl_xor(ds, 32, 64);
  if (lane < 16) {
    float4 sv = hv[(size_t)node * 16 + f4];
    float4 o;
    o.x = (a0 + sv.x * di) * di;
    o.y = (a1 + sv.y * di) * di;
    o.z = (a2 + sv.z * di) * di;
    o.w = (a3 + sv.w * di) * di;
    ((float4*)y)[(size_t)node * 16 + f4] = o;
    if (f4 == 0) gout[node] = di * (ds + di * di);
  }
}

// ---------------- x1 = y @ Wc + g * bc ----------------

__global__ __launch_bounds__(256, 2) void k_gemm1(const float* __restrict__ y, const float* __restrict__ gin,
                                                  const float* __restrict__ Wc, const float* __restrict__ bc,
                                                  float* __restrict__ x1, int N) {
  const int lane = threadIdx.x & 63;
  float w0[64], w1[64];
#pragma unroll
  for (int d = 0; d < 64; ++d) {
    w0[d] = Wc[d * 128 + lane];
    w1[d] = Wc[d * 128 + 64 + lane];
  }
  const float b0 = bc[lane], b1v = bc[64 + lane];
  const int nw = (gridDim.x * blockDim.x) >> 6;
  const int w_id = (blockIdx.x * blockDim.x + threadIdx.x) >> 6;
  for (int r = w_id; r < N; r += nw) {
    const float xv = y[(size_t)r * 64 + lane];
    const float gr = gin[r];
    const int xi = __float_as_int(xv);
    float p0 = 0.f, p1 = 0.f, p2 = 0.f, p3 = 0.f;
#pragma unroll
    for (int d0 = 0; d0 < 64; d0 += 2) {
      float a0 = RL((float&)xi, d0);
      float a1 = RL((float&)xi, d0 + 1);
      p0 += a0 * w0[d0];
      p1 += a0 * w1[d0];
      p2 += a1 * w0[d0 + 1];
      p3 += a1 * w1[d0 + 1];
    }
    size_t o = (size_t)r * 128 + lane;
    x1[o] = p0 + p2 + gr * b0;
    x1[o + 64] = p1 + p3 + gr * b1v;
  }
}

// ---------------- h2p = (relu(x1 + b1) @ W2) * dinv[r] ----------------

__global__ __launch_bounds__(256, 2) void k_gemm2(const float* __restrict__ x1, const float* __restrict__ b1,
                                                  const float* __restrict__ W2, const float* __restrict__ dinv,
                                                  float* __restrict__ h2p, int N) {
  const int lane = threadIdx.x & 63;
  const int col = lane & 31;
  float w[128];
#pragma unroll
  for (int d = 0; d < 128; ++d) w[d] = W2[d * 32 + col];
  const float bb0 = b1[lane], bb1 = b1[64 + lane];
  const int nw = (gridDim.x * blockDim.x) >> 6;
  const int w_id = (blockIdx.x * blockDim.x + threadIdx.x) >> 6;
  for (int r = w_id; r < N; r += nw) {
    float rx0 = fmaxf(x1[(size_t)r * 128 + lane] + bb0, 0.f);
    float rx1 = fmaxf(x1[(size_t)r * 128 + 64 + lane] + bb1, 0.f);
    const int xi0 = __float_as_int(rx0), xi1 = __float_as_int(rx1);
    float p0 = 0.f, p1 = 0.f, p2 = 0.f, p3 = 0.f;
#pragma unroll
    for (int d0 = 0; d0 < 64; d0 += 2) {
      float a0 = RL((float&)xi0, d0);
      float a1 = RL((float&)xi0, d0 + 1);
      float c0 = RL((float&)xi1, d0);
      float c1 = RL((float&)xi1, d0 + 1);
      p0 += a0 * w[d0];
      p1 += a1 * w[d0 + 1];
      p2 += c0 * w[64 + d0];
      p3 += c1 * w[64 + d0 + 1];
    }
    if (lane < 32) {
      float di = dinv[r];
      h2p[(size_t)r * 32 + col] = ((p0 + p1) + (p2 + p3)) * di;
    }
  }
}

// ---------------- fused layer-2 gather + query MLP ----------------

__global__ __launch_bounds__(256) void k_gmlp(const int* __restrict__ qidx, const int* __restrict__ row,
                                              const int* __restrict__ cnt, const int* __restrict__ esrc,
                                              const float* __restrict__ h2p, const float* __restrict__ dinv,
                                              const float* __restrict__ b2, const float* __restrict__ Wm1,
                                              const float* __restrict__ bm1, const float* __restrict__ Wm2,
                                              const float* __restrict__ bm2, float* __restrict__ out, int B) {
  __shared__ float qs[4][32];
  const int lane = threadIdx.x & 63;
  const int wv = threadIdx.x >> 6;
  const int w = blockIdx.x * 4 + wv;            // query id
  const int wc = (w < B) ? w : (B - 1);         // clamp (keep block barrier-uniform)
  const int node = RFL(qidx[wc]);

  const int q = lane >> 3, f4 = lane & 7;       // group 0..7, float4 slot 0..7
  const int rs = RFL(row[node]);
  const int ne = RFL(cnt[node]);
  const float di = dinv[node];
  const float4* __restrict__ hv = (const float4*)h2p;
  float a0 = 0.f, a1 = 0.f, a2 = 0.f, a3 = 0.f;
  int j = 0;
  for (; j + 32 <= ne; j += 32) {
    const int b = rs + j + q * 4;
    int s[4];
#pragma unroll
    for (int u = 0; u < 4; ++u) s[u] = esrc[b + u];
    float4 v[4];
#pragma unroll
    for (int u = 0; u < 4; ++u) v[u] = hv[(size_t)s[u] * 8 + f4];
#pragma unroll
    for (int u = 0; u < 4; ++u) {
      a0 += v[u].x; a1 += v[u].y; a2 += v[u].z; a3 += v[u].w;
    }
  }
  if (j < ne) {
    const int b = j + q * 4;
    int s[4];
    float m[4];
#pragma unroll
    for (int u = 0; u < 4; ++u) {
      int idx = b + u;
      int c = (idx < ne) ? idx : (ne - 1);
      s[u] = esrc[rs + c];
      m[u] = (idx < ne) ? 1.f : 0.f;
    }
    float4 v[4];
#pragma unroll
    for (int u = 0; u < 4; ++u) v[u] = hv[(size_t)s[u] * 8 + f4];
#pragma unroll
    for (int u = 0; u < 4; ++u) {
      a0 += v[u].x * m[u]; a1 += v[u].y * m[u]; a2 += v[u].z * m[u]; a3 += v[u].w * m[u];
    }
  }
#pragma unroll
  for (int off = 8; off <= 32; off <<= 1) {
    a0 += __shfl_xor(a0, off, 64);
    a1 += __shfl_xor(a1, off, 64);
    a2 += __shfl_xor(a2, off, 64);
    a3 += __shfl_xor(a3, off, 64);
  }
  if (q == 0) {  // lanes 0..7 hold the final x2 float4s
    float4 sv = hv[(size_t)node * 8 + f4];
    qs[wv][f4 * 4 + 0] = fmaxf((a0 + sv.x * di) * di + b2[f4 * 4 + 0], 0.f);
    qs[wv][f4 * 4 + 1] = fmaxf((a1 + sv.y * di) * di + b2[f4 * 4 + 1], 0.f);
    qs[wv][f4 * 4 + 2] = fmaxf((a2 + sv.z * di) * di + b2[f4 * 4 + 2], 0.f);
    qs[wv][f4 * 4 + 3] = fmaxf((a3 + sv.w * di) * di + b2[f4 * 4 + 3], 0.f);
  }
  __syncthreads();

  float h = bm1[lane];
#pragma unroll
  for (int k = 0; k < 32; ++k) h += qs[wv][k] * Wm1[k * 64 + lane];
  float r = fmaxf(h, 0.f) * Wm2[lane];
#pragma unroll
  for (int off = 1; off < 64; off <<= 1) r += __shfl_xor(r, off, 64);
  if (lane == 0 && w < B) out[w] = r + bm2[0];
}

// ---------------- launcher ----------------

extern "C" void kernel_launch(void* const* d_in, const int* in_sizes, int n_in,
                              void* d_out, int out_size, void* d_ws, size_t ws_size,
                              hipStream_t stream) {
  const float* X    = (const float*)d_in[0];
  const int*   mask = (const int*)d_in[1];
  const int*   ei   = (const int*)d_in[2];
  const int*   qidx = (const int*)d_in[3];
  const float* WE   = (const float*)d_in[4];
  const float* bE   = (const float*)d_in[5];
  const float* WA   = (const float*)d_in[6];
  const float* bA   = (const float*)d_in[7];
  const float* Wout = (const float*)d_in[8];
  const float* bout = (const float*)d_in[9];
  const float* W1   = (const float*)d_in[10];
  const float* b1   = (const float*)d_in[11];
  const float* W2   = (const float*)d_in[12];
  const float* b2   = (const float*)d_in[13];
  const float* Wm1  = (const float*)d_in[14];
  const float* bm1  = (const float*)d_in[15];
  const float* Wm2  = (const float*)d_in[16];
  const float* bm2  = (const float*)d_in[17];

  const int N = in_sizes[1] / 20;
  const int E = in_sizes[2] / 2;
  const int B = in_sizes[3];
  const int* src  = ei;
  const int* dstp = ei + E;

  const size_t Na = ((size_t)N + 63) & ~(size_t)63;
  const size_t Ea = ((size_t)E + 63) & ~(size_t)63;
  const int P = (N + 255) / 256;
  const size_t Pa = ((size_t)P + 63) & ~(size_t)63;

  float* ws      = (float*)d_ws;
  float* dinv    = ws;                       // N
  int*   cnt     = (int*)(dinv + Na);        // N
  int*   rowp    = cnt + Na;                 // N
  int*   cursor  = rowp + Na;                // N
  int*   partial = cursor + Na;              // P
  int*   esrc    = partial + Pa;             // E
  float* Wc      = (float*)(esrc + Ea);      // 8192
  float* bc      = Wc + 8192;                // 128
  float* gbuf    = bc + 128;                 // N
  float* pzp     = gbuf + Na;                // N*64
  float* y       = pzp + (size_t)N * 64;     // N*64
  float* x1      = y + (size_t)N * 64;       // N*128
  float* h2p     = pzp;                      // reuse pzp (dead after gather1): N*32

  const int nb = (N + 255) / 256;
  const int nw4 = (N + 3) / 4;
  const int poolBlocks = ((N + 3) / 4 < 768) ? (N + 3) / 4 : 768;

  k_zero<<<nb, 256, 0, stream>>>(cnt, N);
  k_count<<<1024, 256, 0, stream>>>(dstp, cnt, E);
  k_scan1<<<P, 256, 0, stream>>>(cnt, rowp, partial, N);
  k_scan3<<<P, 256, 0, stream>>>(rowp, partial, cursor, cnt, dinv, N);
  k_edge_fill<<<2048, 256, 0, stream>>>(src, dstp, cursor, esrc, E);
  k_wc<<<33, 256, 0, stream>>>(Wout, bout, W1, Wc, bc);
  k_pool<<<poolBlocks, 256, 0, stream>>>(X, mask, WE, bE, WA, bA, dinv, pzp, N);
  k_gather1<<<nw4, 256, 0, stream>>>(rowp, cnt, esrc, pzp, dinv, y, gbuf, N);
  k_gemm1<<<1024, 256, 0, stream>>>(y, gbuf, Wc, bc, x1, N);
  k_gemm2<<<1024, 256, 0, stream>>>(x1, b1, W2, dinv, h2p, N);
  k_gmlp<<<(B + 3) / 4, 256, 0, stream>>>(qidx, rowp, cnt, esrc, h2p, dinv, b2, Wm1, bm1, Wm2, bm2,
                                          (float*)d_out, B);
}